// Round 1
// baseline (477.464 us; speedup 1.0000x reference)
//
#include <hip/hip_runtime.h>
#include <hip/hip_bf16.h>

typedef __attribute__((ext_vector_type(8))) short short8;
typedef __attribute__((ext_vector_type(4))) float f32x4;
typedef unsigned short u16;

#define DEV static __device__ __forceinline__

constexpr int Bsz = 4, Tn = 2048, Cn = 1024, Hn = 16, Dn = 64;

DEV u16 f2bf(float f) {
    union { float f; unsigned u; } v{f};
    unsigned u = v.u;
    unsigned r = (u + 0x7fffu + ((u >> 16) & 1u)) >> 16;
    return (u16)r;
}
DEV float bf2f(u16 u) {
    union { unsigned u; float f; } v;
    v.u = ((unsigned)u) << 16;
    return v.f;
}

DEV void gload_lds16(const void* g, void* l) {
    __builtin_amdgcn_global_load_lds((const __attribute__((address_space(1))) void*)g,
                                     (__attribute__((address_space(3))) void*)l, 16, 0, 0);
}

// ---------------- fp32 -> bf16 convert (vectorized) ----------------
__global__ void cvt_kernel(const float* __restrict__ in, u16* __restrict__ out, int n4) {
    int i = blockIdx.x * blockDim.x + threadIdx.x;
    int stride = gridDim.x * blockDim.x;
    for (; i < n4; i += stride) {
        float4 v = ((const float4*)in)[i];
        short4 o;
        o.x = (short)f2bf(v.x); o.y = (short)f2bf(v.y);
        o.z = (short)f2bf(v.z); o.w = (short)f2bf(v.w);
        ((short4*)out)[i] = o;
    }
}

// ---------------- RoPE trig tables [T][32] ----------------
__global__ void trig_kernel(float* __restrict__ cs, float* __restrict__ sn) {
    int idx = blockIdx.x * blockDim.x + threadIdx.x; // Tn*32
    int t = idx >> 5, i = idx & 31;
    double inv = pow(10000.0, -(double)i / 32.0);
    double a = (double)t * inv;
    cs[idx] = (float)cos(a);
    sn[idx] = (float)sin(a);
}

// ---------------- RoPE in place on [B,H,T,D] bf16 ----------------
__global__ void rope_kernel(u16* __restrict__ q, const float* __restrict__ cs,
                            const float* __restrict__ sn, int nrows) {
    int idx = blockIdx.x * blockDim.x + threadIdx.x;
    if (idx >= nrows * 32) return;
    int row = idx >> 5, i = idx & 31;
    int t = row & (Tn - 1); // row = (b*H+h)*T + t
    float c = cs[(t << 5) + i], s = sn[(t << 5) + i];
    u16* p = q + ((long)row << 6);
    float x1 = bf2f(p[i]), x2 = bf2f(p[i + 32]);
    p[i]      = f2bf(x1 * c - x2 * s);
    p[i + 32] = f2bf(x2 * c + x1 * s);
}

// ---------------- 128x128 bf16 GEMM, C = A * B^T ----------------
// A: [M,K] bf16 row-major. B: [N,K] bf16 row-major (= weight as stored).
// MODE 0: write bf16 transposed to [B,H,T,D]; grid.z selects (B0/B1/B2, O0/O1/O2).
// MODE 1: write fp32 row-major [M,N].
template <int MODE>
__global__ __launch_bounds__(256, 2) void gemm_bt(
    const u16* __restrict__ A,
    const u16* __restrict__ B0, const u16* __restrict__ B1, const u16* __restrict__ B2,
    void* __restrict__ O0, void* __restrict__ O1, void* __restrict__ O2,
    int M, int N, int K) {
    __shared__ u16 As[128 * 32];
    __shared__ u16 Bs[128 * 32];

    const u16* Bp = B0;
    void* Op = O0;
    if (MODE == 0) {
        if (blockIdx.z == 1) { Bp = B1; Op = O1; }
        else if (blockIdx.z == 2) { Bp = B2; Op = O2; }
    }
    int tid = threadIdx.x;
    int w = tid >> 6, lane = tid & 63;
    int lr = lane & 15, lg = lane >> 4;
    int wr = w >> 1, wc = w & 1;
    long brow = (long)blockIdx.x * 128, bcol = (long)blockIdx.y * 128;

    f32x4 acc[4][4] = {};
    const u16* Arow = A + brow * K;
    const u16* Brow = Bp + bcol * K;

    for (int k0 = 0; k0 < K; k0 += 32) {
        __syncthreads();
#pragma unroll
        for (int c = 0; c < 2; c++) {
            int idx = c * 256 + tid;
            int row = idx >> 2, col = (idx & 3) << 3;
            const u16* ga = Arow + (long)row * K + k0 + col;
            const u16* gb = Brow + (long)row * K + k0 + col;
            char* la = (char*)As + (size_t)(c * 256 + (tid & 192)) * 16;
            char* lb = (char*)Bs + (size_t)(c * 256 + (tid & 192)) * 16;
            gload_lds16(ga, la);
            gload_lds16(gb, lb);
        }
        __syncthreads();
        short8 a[4], b[4];
#pragma unroll
        for (int i = 0; i < 4; i++)
            a[i] = *(const short8*)&As[(64 * wr + 16 * i + lr) * 32 + lg * 8];
#pragma unroll
        for (int j = 0; j < 4; j++)
            b[j] = *(const short8*)&Bs[(64 * wc + 16 * j + lr) * 32 + lg * 8];
#pragma unroll
        for (int i = 0; i < 4; i++)
#pragma unroll
            for (int j = 0; j < 4; j++)
                acc[i][j] = __builtin_amdgcn_mfma_f32_16x16x32_bf16(a[i], b[j], acc[i][j], 0, 0, 0);
    }

#pragma unroll
    for (int i = 0; i < 4; i++)
#pragma unroll
        for (int j = 0; j < 4; j++)
#pragma unroll
            for (int jj = 0; jj < 4; jj++) {
                long gr = brow + 64 * wr + 16 * i + lg * 4 + jj;
                long gc = bcol + 64 * wc + 16 * j + lr;
                float v = acc[i][j][jj];
                if (MODE == 0) {
                    long b_ = gr >> 11, t_ = gr & 2047, h_ = gc >> 6, d_ = gc & 63;
                    ((u16*)Op)[(((b_ * Hn + h_) * Tn + t_) << 6) + d_] = f2bf(v);
                } else {
                    ((float*)Op)[gr * N + gc] = v;
                }
            }
}

// ---------------- flash attention, causal, D=64 ----------------
// Q,K,V: [B*H, T, 64] bf16 (rope already applied to Q,K).
// Yb out: [B, T, C] bf16. Each wave owns 16 q-rows independently.
__global__ __launch_bounds__(256, 2) void attn_kernel(
    const u16* __restrict__ Q, const u16* __restrict__ K, const u16* __restrict__ V,
    u16* __restrict__ Yb) {
    __shared__ u16 plds[4][16][72]; // +8 pad: row stride 144B (16B-aligned, banks spread)

    int tid = threadIdx.x;
    int w = tid >> 6, lane = tid & 63;
    int lr = lane & 15, lg = lane >> 4;
    int qb = blockIdx.x * 4 + w;
    int q0 = qb * 16;
    long bh = blockIdx.y;
    const u16* Qp = Q + bh * Tn * Dn;
    const u16* Kp = K + bh * Tn * Dn;
    const u16* Vp = V + bh * Tn * Dn;
    const float scale = 0.125f; // D^-0.5

    short8 aq[2];
#pragma unroll
    for (int ks = 0; ks < 2; ks++)
        aq[ks] = *(const short8*)&Qp[(long)(q0 + lr) * 64 + ks * 32 + lg * 8];

    f32x4 acc_o[4] = {};
    float m_[4], l_[4];
#pragma unroll
    for (int jj = 0; jj < 4; jj++) { m_[jj] = -1e30f; l_[jj] = 0.f; }

    int kv_end = q0 + 16;
    for (int kv0 = 0; kv0 < kv_end; kv0 += 64) {
        f32x4 s[4];
#pragma unroll
        for (int cblk = 0; cblk < 4; cblk++) {
            f32x4 sc = {};
#pragma unroll
            for (int ks = 0; ks < 2; ks++) {
                short8 bk = *(const short8*)&Kp[(long)(kv0 + cblk * 16 + lr) * 64 + ks * 32 + lg * 8];
                sc = __builtin_amdgcn_mfma_f32_16x16x32_bf16(aq[ks], bk, sc, 0, 0, 0);
            }
            int col = kv0 + cblk * 16 + lr;
#pragma unroll
            for (int jj = 0; jj < 4; jj++) {
                int row = q0 + lg * 4 + jj;
                float v = sc[jj] * scale;
                if (col > row) v = -1e30f;
                sc[jj] = v;
            }
            s[cblk] = sc;
        }
        // wave-parallel row max over 64 cols (16 lanes x 4 cblk)
#pragma unroll
        for (int jj = 0; jj < 4; jj++) {
            float v = fmaxf(fmaxf(s[0][jj], s[1][jj]), fmaxf(s[2][jj], s[3][jj]));
            v = fmaxf(v, __shfl_xor(v, 1));
            v = fmaxf(v, __shfl_xor(v, 2));
            v = fmaxf(v, __shfl_xor(v, 4));
            v = fmaxf(v, __shfl_xor(v, 8));
            float mn = fmaxf(m_[jj], v);
            float alpha = __expf(m_[jj] - mn);
            m_[jj] = mn;
            float sum = 0.f;
#pragma unroll
            for (int cblk = 0; cblk < 4; cblk++) {
                float p = __expf(s[cblk][jj] - mn);
                s[cblk][jj] = p;
                sum += p;
            }
            sum += __shfl_xor(sum, 1);
            sum += __shfl_xor(sum, 2);
            sum += __shfl_xor(sum, 4);
            sum += __shfl_xor(sum, 8);
            l_[jj] = l_[jj] * alpha + sum;
            acc_o[0][jj] *= alpha; acc_o[1][jj] *= alpha;
            acc_o[2][jj] *= alpha; acc_o[3][jj] *= alpha;
        }
        // P (C-layout) -> LDS -> A-frags (layout fix-up); same-wave, no barrier
#pragma unroll
        for (int cblk = 0; cblk < 4; cblk++)
#pragma unroll
            for (int jj = 0; jj < 4; jj++)
                plds[w][lg * 4 + jj][cblk * 16 + lr] = f2bf(s[cblk][jj]);
        short8 pa[2];
#pragma unroll
        for (int ks = 0; ks < 2; ks++)
            pa[ks] = *(const short8*)&plds[w][lr][ks * 32 + lg * 8];
        // PV: B-frag from V rows (stride-64 scalar loads; L2-resident)
#pragma unroll
        for (int ks = 0; ks < 2; ks++) {
#pragma unroll
            for (int dblk = 0; dblk < 4; dblk++) {
                short8 bv;
                const u16* vb = Vp + (long)(kv0 + ks * 32 + lg * 8) * 64 + dblk * 16 + lr;
#pragma unroll
                for (int j = 0; j < 8; j++) bv[j] = (short)vb[(long)j * 64];
                acc_o[dblk] = __builtin_amdgcn_mfma_f32_16x16x32_bf16(pa[ks], bv, acc_o[dblk], 0, 0, 0);
            }
        }
    }
    // epilogue: y / l, write [B,T,C] bf16
    long b_ = bh / Hn, h_ = bh % Hn;
#pragma unroll
    for (int dblk = 0; dblk < 4; dblk++)
#pragma unroll
        for (int jj = 0; jj < 4; jj++) {
            int row = q0 + lg * 4 + jj;
            int d = dblk * 16 + lr;
            float v = acc_o[dblk][jj] / l_[jj];
            Yb[((b_ * Tn + row) * Cn) + h_ * 64 + d] = f2bf(v);
        }
}

extern "C" void kernel_launch(void* const* d_in, const int* in_sizes, int n_in,
                              void* d_out, int out_size, void* d_ws, size_t ws_size,
                              hipStream_t stream) {
    const float* x  = (const float*)d_in[0];
    const float* wq = (const float*)d_in[1];
    const float* wk = (const float*)d_in[2];
    const float* wv = (const float*)d_in[3];
    const float* wp = (const float*)d_in[4];

    char* ws = (char*)d_ws;
    size_t off = 0;
    auto alloc = [&](size_t bytes) {
        char* p = ws + off;
        off += (bytes + 255) & ~(size_t)255;
        return p;
    };
    const size_t BTC = (size_t)Bsz * Tn * Cn;
    u16* xb  = (u16*)alloc(BTC * 2);
    u16* wqb = (u16*)alloc((size_t)Cn * Cn * 2);
    u16* wkb = (u16*)alloc((size_t)Cn * Cn * 2);
    u16* wvb = (u16*)alloc((size_t)Cn * Cn * 2);
    u16* wpb = (u16*)alloc((size_t)Cn * Cn * 2);
    u16* qr  = (u16*)alloc(BTC * 2);
    u16* kr  = (u16*)alloc(BTC * 2);
    u16* vr  = (u16*)alloc(BTC * 2);
    u16* yb  = (u16*)alloc(BTC * 2);
    float* cs = (float*)alloc((size_t)Tn * 32 * 4);
    float* sn = (float*)alloc((size_t)Tn * 32 * 4);

    int M = Bsz * Tn; // 8192
    cvt_kernel<<<1024, 256, 0, stream>>>(x, xb, (int)(BTC / 4));
    cvt_kernel<<<256, 256, 0, stream>>>(wq, wqb, Cn * Cn / 4);
    cvt_kernel<<<256, 256, 0, stream>>>(wk, wkb, Cn * Cn / 4);
    cvt_kernel<<<256, 256, 0, stream>>>(wv, wvb, Cn * Cn / 4);
    cvt_kernel<<<256, 256, 0, stream>>>(wp, wpb, Cn * Cn / 4);
    trig_kernel<<<(Tn * 32) / 256, 256, 0, stream>>>(cs, sn);

    // QKV projections -> [B,H,T,D] bf16
    gemm_bt<0><<<dim3(M / 128, Cn / 128, 3), 256, 0, stream>>>(
        xb, wqb, wkb, wvb, qr, kr, vr, M, Cn, Cn);

    int nrows = Bsz * Hn * Tn; // 131072
    rope_kernel<<<(nrows * 32) / 256, 256, 0, stream>>>(qr, cs, sn, nrows);
    rope_kernel<<<(nrows * 32) / 256, 256, 0, stream>>>(kr, cs, sn, nrows);

    attn_kernel<<<dim3(Tn / 64, Bsz * Hn), 256, 0, stream>>>(qr, kr, vr, yb);

    // output projection -> fp32 d_out
    gemm_bt<1><<<dim3(M / 128, Cn / 128, 1), 256, 0, stream>>>(
        yb, wpb, wpb, wpb, d_out, nullptr, nullptr, M, Cn, Cn);
}